// Round 8
// baseline (2065.848 us; speedup 1.0000x reference)
//
#include <hip/hip_runtime.h>
#include <hip/hip_bf16.h>
#include <stdint.h>

#define NB 128
#define NT 512
#define NI 256
#define NH 256
#define NG 768          // 3*NH

typedef unsigned int u32;
typedef unsigned short u16;
typedef __attribute__((ext_vector_type(8))) short short8;
typedef __attribute__((ext_vector_type(4))) float f32x4;

__device__ __forceinline__ float lo_bf(u32 u){ return __uint_as_float(u << 16); }
__device__ __forceinline__ float hi_bf(u32 u){ return __uint_as_float(u & 0xffff0000u); }
__device__ __forceinline__ u16 f2bf(float f){
  u32 u = __float_as_uint(f);
  u += 0x7fffu + ((u >> 16) & 1u);   // RNE
  return (u16)(u >> 16);
}
__device__ __forceinline__ u32 pack2(float a, float b){
  return (u32)f2bf(a) | ((u32)f2bf(b) << 16);
}
__device__ __forceinline__ u32 pack_rne(float a, float b){
  u32 ua = __float_as_uint(a), ub = __float_as_uint(b);
  ua += 0x7fffu + ((ua >> 16) & 1u);
  ub += 0x7fffu + ((ub >> 16) & 1u);
  return (ua >> 16) | (ub & 0xffff0000u);
}
__device__ __forceinline__ float sigf(float v){
  return __builtin_amdgcn_rcpf(1.f + __expf(-v));
}
__device__ __forceinline__ float tanhf_(float u){
  float e = __expf(2.f*u);
  return 1.f - 2.f*__builtin_amdgcn_rcpf(e + 1.f);
}
__device__ __forceinline__ void gload_lds16(const void* g, void* l){
  __builtin_amdgcn_global_load_lds((const __attribute__((address_space(1))) void*)g,
                                   (__attribute__((address_space(3))) void*)l, 16, 0, 0);
}

// ---------------------------------------------------------------------------
// fp32 -> bf16 conversions + combined bias vectors (both layers)
// ---------------------------------------------------------------------------
__global__ void convert_kernel(const float* __restrict__ x,
    const float* __restrict__ Wih0, const float* __restrict__ Wih1,
    const float* __restrict__ bih0, const float* __restrict__ bhh0,
    const float* __restrict__ bih1, const float* __restrict__ bhh1,
    u16* __restrict__ xbf, u16* __restrict__ w0bf, u16* __restrict__ w1bf,
    float* __restrict__ bias0, float* __restrict__ bias1)
{
  const int NX4 = NB*NT*NI/4, NW4 = NG*NH/4;
  int gid = blockIdx.x*blockDim.x + threadIdx.x;
  for (int i = gid; i < NX4 + 2*NW4; i += gridDim.x*blockDim.x) {
    const float* s; u16* d; int o;
    if (i < NX4)          { s = x;    d = xbf;  o = i; }
    else if (i < NX4+NW4) { s = Wih0; d = w0bf; o = i - NX4; }
    else                  { s = Wih1; d = w1bf; o = i - NX4 - NW4; }
    float4 v = *(const float4*)(s + (size_t)o*4);
    uint2 pk; pk.x = pack2(v.x, v.y); pk.y = pack2(v.z, v.w);
    *(uint2*)&d[(size_t)o*4] = pk;
  }
  if (gid < NG)            bias0[gid] = bih0[gid] + (gid < 2*NH ? bhh0[gid] : 0.f);
  else if (gid < 2*NG)   { int g = gid - NG; bias1[g] = bih1[g] + (g < 2*NH ? bhh1[g] : 0.f); }
}

// ---------------------------------------------------------------------------
// xproj[m][g] = sum_k A[m][k] * W[g][k] + bias[g]    (A:[M][256], W:[768][256])
// ---------------------------------------------------------------------------
__global__ __launch_bounds__(256, 2) void gemm_proj(const u16* __restrict__ A,
    const u16* __restrict__ W, const float* __restrict__ bias, u16* __restrict__ out)
{
  const int mt = blockIdx.x / 24, nt = blockIdx.x % 24;
  __shared__ __align__(16) u16 As[64*256];
  __shared__ __align__(16) u16 Bs[32*256];
  const int tid = threadIdx.x;
  const u16* Ag = A + (size_t)mt*64*256;
  const u16* Wg = W + (size_t)nt*32*256;
  #pragma unroll
  for (int i = 0; i < 8; ++i) {
    int ca = tid + 256*i, row = ca >> 5, sl = ca & 31;
    gload_lds16(Ag + row*256 + ((sl ^ (row&7))<<3), &As[ca<<3]);
  }
  #pragma unroll
  for (int i = 0; i < 4; ++i) {
    int cb = tid + 256*i, row = cb >> 5, sl = cb & 31;
    gload_lds16(Wg + row*256 + ((sl ^ (row&7))<<3), &Bs[cb<<3]);
  }
  __syncthreads();
  const int w = tid >> 6, l = tid & 63, c = l & 15, q = l >> 4;
  f32x4 acc0 = {0.f,0.f,0.f,0.f}, acc1 = acc0;
  const int arow = w*16 + c;
  #pragma unroll
  for (int kb = 0; kb < 8; ++kb) {
    int ks = kb*4 + q;
    short8 af  = *(const short8*)&As[arow*256 + ((ks ^ (arow&7))<<3)];
    short8 bf0 = *(const short8*)&Bs[c*256        + ((ks ^ (c&7))<<3)];
    short8 bf1 = *(const short8*)&Bs[(16+c)*256   + ((ks ^ ((16+c)&7))<<3)];
    acc0 = __builtin_amdgcn_mfma_f32_16x16x32_bf16(af, bf0, acc0, 0,0,0);
    acc1 = __builtin_amdgcn_mfma_f32_16x16x32_bf16(af, bf1, acc1, 0,0,0);
  }
  #pragma unroll
  for (int nf = 0; nf < 2; ++nf) {
    int g = nt*32 + nf*16 + c;
    float bs = bias[g];
    f32x4 av = nf ? acc1 : acc0;
    #pragma unroll
    for (int r = 0; r < 4; ++r) {
      int m = mt*64 + w*16 + q*4 + r;
      out[(size_t)m*NG + g] = f2bf(av[r] + bs);
    }
  }
}

// ---------------------------------------------------------------------------
// GRU recurrence v3: 32 wgs x 512 thr, 4 batches per wg (4x column dup).
// Wave w owns j in [32w,32w+32), all 3 gates, weights resident (48 frags).
// Lane (c,q): batch=c&3, jh=c>>3, rpair=(c>>2)&1 -> computes 2 h-values
// (j0 = 32w+16jh+4q+2*rpair, j0+1). 12 TRANS/lane (was 24).
// ---------------------------------------------------------------------------
__global__ __launch_bounds__(512, 1) void recur_kernel(
    const u16* __restrict__ xproj,   // [NB*NT][768] bf16 (biases folded; r,z incl bhh)
    const float* __restrict__ Whh,   // [768][256] fp32
    const float* __restrict__ bhh,   // [768] fp32 (n part used)
    u16* __restrict__ outp,          // write_all: [NB][NT][256] ; else hT [NB][256]
    int write_all)
{
  const int b0 = blockIdx.x * 4;
  const int tid = threadIdx.x;
  const int w = tid >> 6, l = tid & 63, c = l & 15, q = l >> 4;
  const int jh = c >> 3;                 // tile half
  const int rs = (c >> 2) & 1;           // r-pair within tile
  const bool lo8 = (jh == 0);
  const bool rlo = (rs == 0);
  const int bb = b0 + (c & 3);           // this lane's batch
  const int j0 = 32*w + jh*16 + q*4 + 2*rs;   // lane's first output j

  __shared__ __align__(16) u16 hfrag[2][8][512];   // 16 KB (B-frags of full h)
  for (int i = tid; i < 4096; i += 512) ((u32*)hfrag)[i] = 0u;

  // ---- resident weight fragments wf[gate][jj][kb] (48 frags) ----
  short8 wf[3][2][8];
  #pragma unroll
  for (int g = 0; g < 3; ++g)
    #pragma unroll
    for (int jj = 0; jj < 2; ++jj) {
      const float* src = Whh + ((size_t)(g*NH + 32*w + jj*16 + c))*NI + q*8;
      #pragma unroll
      for (int kb = 0; kb < 8; ++kb) {
        float4 f0 = *(const float4*)(src + kb*32);
        float4 f1 = *(const float4*)(src + kb*32 + 4);
        short8 s;
        s[0]=(short)f2bf(f0.x); s[1]=(short)f2bf(f0.y);
        s[2]=(short)f2bf(f0.z); s[3]=(short)f2bf(f0.w);
        s[4]=(short)f2bf(f1.x); s[5]=(short)f2bf(f1.y);
        s[6]=(short)f2bf(f1.z); s[7]=(short)f2bf(f1.w);
        wf[g][jj][kb] = s;
      }
    }

  // n-gate hidden-bias as accumulator init (rows q*4..+3 of each tile)
  float4 bt0 = *(const float4*)&bhh[2*NH + 32*w + q*4];
  float4 bt1 = *(const float4*)&bhh[2*NH + 32*w + q*4 + 16];
  f32x4 bhn0; bhn0[0]=bt0.x; bhn0[1]=bt0.y; bhn0[2]=bt0.z; bhn0[3]=bt0.w;
  f32x4 bhn1; bhn1[0]=bt1.x; bhn1[1]=bt1.y; bhn1[2]=bt1.z; bhn1[3]=bt1.w;

  // xproj pointers (per-lane): column g*NH + j0, row m = bb*NT + t
  const u16* xptr = xproj + (size_t)bb*NT*NG + j0;
  u32 xpr = *(const u32*)(xptr);
  u32 xpz = *(const u32*)(xptr + NH);
  u32 xpn = *(const u32*)(xptr + 2*NH);
  const u16* x1 = xptr + NG;
  u32 pfr = *(const u32*)(x1);
  u32 pfz = *(const u32*)(x1 + NH);
  u32 pfn = *(const u32*)(x1 + 2*NH);
  u32 hpk = 0u;                          // own 2 h_prev (bf16 packed)

  // LDS write base: lane-col l' = (c&3) + 16*(2jh + (q>>1)), elem = 4(q&1)+2rs
  const int lpb  = (c & 3) + 16*(2*jh + (q >> 1));
  const int elds = 4*(q & 1) + 2*rs;
  const int woff = lpb*8 + elds;         // u16 units within hfrag[.][w]

  __syncthreads();

  #pragma unroll 1
  for (int t = 0; t < NT; ++t) {
    const int cur = t & 1, nxt = cur ^ 1;

    // ---- B-fragment reads of full h_t ----
    short8 bfr[8];
    #pragma unroll
    for (int kb = 0; kb < 8; ++kb) bfr[kb] = *(const short8*)&hfrag[cur][kb][l*8];

    // ---- 6 independent 8-deep MFMA chains ----
    f32x4 z4 = {0.f,0.f,0.f,0.f};
    f32x4 ar0 = z4, az0 = z4, ar1 = z4, az1 = z4;
    f32x4 an0 = bhn0, an1 = bhn1;
    __builtin_amdgcn_s_setprio(1);
    #pragma unroll
    for (int kb = 0; kb < 8; ++kb) {
      short8 bv = bfr[kb];
      ar0 = __builtin_amdgcn_mfma_f32_16x16x32_bf16(wf[0][0][kb], bv, ar0, 0,0,0);
      az0 = __builtin_amdgcn_mfma_f32_16x16x32_bf16(wf[1][0][kb], bv, az0, 0,0,0);
      an0 = __builtin_amdgcn_mfma_f32_16x16x32_bf16(wf[2][0][kb], bv, an0, 0,0,0);
      ar1 = __builtin_amdgcn_mfma_f32_16x16x32_bf16(wf[0][1][kb], bv, ar1, 0,0,0);
      az1 = __builtin_amdgcn_mfma_f32_16x16x32_bf16(wf[1][1][kb], bv, az1, 0,0,0);
      an1 = __builtin_amdgcn_mfma_f32_16x16x32_bf16(wf[2][1][kb], bv, an1, 0,0,0);
    }
    __builtin_amdgcn_s_setprio(0);

    // ---- extraction: 2 values per gate (jh- and rpair-select) ----
    float hv[2];
    #pragma unroll
    for (int e = 0; e < 2; ++e) {
      float a0 = rlo ? ar0[e] : ar0[2+e];
      float a1 = rlo ? ar1[e] : ar1[2+e];
      float arv = lo8 ? a0 : a1;
      float z0 = rlo ? az0[e] : az0[2+e];
      float z1 = rlo ? az1[e] : az1[2+e];
      float azv = lo8 ? z0 : z1;
      float n0 = rlo ? an0[e] : an0[2+e];
      float n1 = rlo ? an1[e] : an1[2+e];
      float anv = lo8 ? n0 : n1;         // includes bhh_n via init
      float xr = e ? hi_bf(xpr) : lo_bf(xpr);
      float xz = e ? hi_bf(xpz) : lo_bf(xpz);
      float xn = e ? hi_bf(xpn) : lo_bf(xpn);
      float hp = e ? hi_bf(hpk) : lo_bf(hpk);
      float rr = sigf(xr + arv);
      float zz = sigf(xz + azv);
      float nn = tanhf_(__builtin_fmaf(rr, anv, xn));
      hv[e] = __builtin_fmaf(zz, hp - nn, nn);   // (1-z)n + z h
    }
    hpk = pack_rne(hv[0], hv[1]);

    // ---- write h into next B-frag: 4 duplicated column copies (b32 each) ----
    u16* hd = &hfrag[nxt][w][woff];
    *(u32*)(hd)       = hpk;
    *(u32*)(hd + 32)  = hpk;
    *(u32*)(hd + 64)  = hpk;
    *(u32*)(hd + 96)  = hpk;

    // ---- outputs ----
    if (write_all)
      *(u32*)&outp[((size_t)bb*NT + t)*NH + j0] = hpk;
    else if (t == NT-1)
      *(u32*)&outp[(size_t)bb*NH + j0] = hpk;

    // ---- depth-2 xproj prefetch rotate ----
    xpr = pfr; xpz = pfz; xpn = pfn;
    if (t + 2 < NT) {
      const u16* xn_ = xptr + (size_t)(t+2)*NG;
      pfr = *(const u32*)(xn_);
      pfz = *(const u32*)(xn_ + NH);
      pfn = *(const u32*)(xn_ + 2*NH);
    }

    // ---- raw barrier: LDS drain only (global stores/prefetch stay in flight)
    asm volatile("s_waitcnt lgkmcnt(0)" ::: "memory");
    __builtin_amdgcn_s_barrier();
    __builtin_amdgcn_sched_barrier(0);
  }
}

// ---------------------------------------------------------------------------
__global__ __launch_bounds__(256) void fc_kernel(const u16* __restrict__ hT,
    const float* __restrict__ Wfc, const float* __restrict__ bfc, float* __restrict__ out)
{
  __shared__ float wv[NH];
  int tid = threadIdx.x;
  if (tid < NH) wv[tid] = Wfc[tid];
  __syncthreads();
  if (tid < NB) {
    float acc = bfc[0];
    for (int j = 0; j < NH; ++j) acc += lo_bf((u32)hT[tid*NH + j]) * wv[j];
    out[tid] = sigf(acc);
  }
}

// ---------------------------------------------------------------------------
extern "C" void kernel_launch(void* const* d_in, const int* in_sizes, int n_in,
                              void* d_out, int out_size, void* d_ws, size_t ws_size,
                              hipStream_t stream) {
  const float* x    = (const float*)d_in[0];
  const float* Wih0 = (const float*)d_in[1];
  const float* Whh0 = (const float*)d_in[2];
  const float* bih0 = (const float*)d_in[3];
  const float* bhh0 = (const float*)d_in[4];
  const float* Wih1 = (const float*)d_in[5];
  const float* Whh1 = (const float*)d_in[6];
  const float* bih1 = (const float*)d_in[7];
  const float* bhh1 = (const float*)d_in[8];
  const float* Wfc  = (const float*)d_in[9];
  const float* bfc  = (const float*)d_in[10];

  char* ws = (char*)d_ws;
  u16*   xproj = (u16*)ws;                                   // 100,663,296 B
  u16*   xbf   = (u16*)(ws + 100663296);                     // 33,554,432 B
  u16*   out0  = xbf;                                        // aliases xbf (dead after GEMM0)
  u16*   w0bf  = (u16*)(ws + 134217728);
  u16*   w1bf  = (u16*)(ws + 134610944);
  float* bias0 = (float*)(ws + 135004160);
  float* bias1 = (float*)(ws + 135007232);
  u16*   hT    = (u16*)(ws + 135010304);

  convert_kernel<<<dim3(2048), dim3(256), 0, stream>>>(
      x, Wih0, Wih1, bih0, bhh0, bih1, bhh1, xbf, w0bf, w1bf, bias0, bias1);
  gemm_proj<<<dim3(1024*24), dim3(256), 0, stream>>>(xbf, w0bf, bias0, xproj);
  recur_kernel<<<dim3(32), dim3(512), 0, stream>>>(xproj, Whh0, bhh0, out0, 1);
  gemm_proj<<<dim3(1024*24), dim3(256), 0, stream>>>(out0, w1bf, bias1, xproj);
  recur_kernel<<<dim3(32), dim3(512), 0, stream>>>(xproj, Whh1, bhh1, hT, 0);
  fc_kernel<<<dim3(1), dim3(256), 0, stream>>>(hT, Wfc, bfc, (float*)d_out);
}